// Round 1
// baseline (260.092 us; speedup 1.0000x reference)
//
#include <hip/hip_runtime.h>

// Problem constants from the reference
#define NB 64
#define NU 9
#define NV 9
#define UV 81          // NU*NV
#define HWSZ 9216      // 96*96
#define MDISP 4
#define WSZ 3          // Chebyshev window half-size

__global__ __launch_bounds__(256) void vcn_kernel(const float* __restrict__ x,
                                                  float* __restrict__ out) {
    int tid = blockIdx.x * blockDim.x + threadIdx.x;
    // grid sized exactly: B*HW = 589824 = 2304 * 256, no bounds check needed
    int b  = tid / HWSZ;
    int hw = tid - b * HWSZ;

    const float* xp = x + (size_t)b * UV * HWSZ + hw;

    // Load all 81 plane values for this pixel into registers (coalesced across lanes).
    float v[UV];
#pragma unroll
    for (int i = 0; i < UV; ++i) v[i] = xp[(size_t)i * HWSZ];

    // Argmax (first occurrence on ties, matching jnp.argmax; ties are measure-zero anyway)
    float m = v[0];
    int idx = 0;
#pragma unroll
    for (int i = 1; i < UV; ++i) {
        if (v[i] > m) { m = v[i]; idx = i; }
    }

    int uc = idx / NV;
    int vc = idx - uc * NV;
    int ulo = uc - WSZ, uhi = uc + WSZ;
    int vlo = vc - WSZ, vhi = vc + WSZ;

    // One pass: e = exp(x - m). Global sums over all 81; local sums over the window.
    float se_g = 0.f;   // sum e (global)
    float sxg  = 0.f;   // sum e*(x-m) (global)
    float se_l = 0.f;   // sum e (window)
    float sxl  = 0.f;   // sum e*(x-m) (window)
    float sfx  = 0.f;   // sum e*(u-4) (window)
    float sfy  = 0.f;   // sum e*(v-4) (window)
#pragma unroll
    for (int u = 0; u < NU; ++u) {
#pragma unroll
        for (int w = 0; w < NV; ++w) {
            float t = v[u * NV + w] - m;
            float e = __expf(t);
            float et = e * t;
            se_g += e;
            sxg  += et;
            bool in = (u >= ulo) & (u <= uhi) & (w >= vlo) & (w <= vhi);
            if (in) {
                se_l += e;
                sxl  += et;
                sfx  += e * (float)(u - MDISP);
                sfy  += e * (float)(w - MDISP);
            }
        }
    }

    float inv_l = 1.f / se_l;
    float inv_g = 1.f / se_g;

    float outx = sfx * inv_l;
    float outy = sfy * inv_l;
    // entropy = log(Z) - E[x-m];  normalize by log(49) / log(81)
    float lent = (__logf(se_l) - sxl * inv_l) * 0.25694895f;  // 1/ln(49)
    float gent = (__logf(se_g) - sxg * inv_g) * 0.22754075f;  // 1/ln(81)

    float* op = out + (size_t)b * 4 * HWSZ + hw;
    op[0 * HWSZ] = outx;
    op[1 * HWSZ] = outy;
    op[2 * HWSZ] = lent;
    op[3 * HWSZ] = gent;
}

extern "C" void kernel_launch(void* const* d_in, const int* in_sizes, int n_in,
                              void* d_out, int out_size, void* d_ws, size_t ws_size,
                              hipStream_t stream) {
    const float* x = (const float*)d_in[0];
    float* out = (float*)d_out;
    const int total = NB * HWSZ;          // 589824
    const int block = 256;
    const int grid = total / block;       // 2304
    vcn_kernel<<<grid, block, 0, stream>>>(x, out);
}